// Round 4
// baseline (320.249 us; speedup 1.0000x reference)
//
#include <hip/hip_runtime.h>
#include <hip/hip_bf16.h>
#include <cstdint>
#include <cstddef>

typedef __hip_bfloat16 bf16;
typedef __attribute__((ext_vector_type(8))) short short8;
typedef __attribute__((ext_vector_type(4))) float floatx4;

#define KO 15360
#define KS 12
#define KSLICE 1280   /* KO / KS, multiple of 64 */

__device__ __forceinline__ float lrelu(float v) { return v > 0.f ? v : 0.01f * v; }

__device__ __forceinline__ float bflo(unsigned int u) {
  unsigned int x = u << 16; float f; __builtin_memcpy(&f, &x, 4); return f;
}
__device__ __forceinline__ float bfhi(unsigned int u) {
  unsigned int x = u & 0xffff0000u; float f; __builtin_memcpy(&f, &x, 4); return f;
}
__device__ __forceinline__ unsigned int pk2(float lo, float hi) {
  bf16 a = __float2bfloat16(lo), b = __float2bfloat16(hi);
  unsigned short ua, ub;
  __builtin_memcpy(&ua, &a, 2); __builtin_memcpy(&ub, &b, 2);
  return (unsigned int)ua | ((unsigned int)ub << 16);
}
// h element pair: lrelu(U+V') packed bf16x2
__device__ __forceinline__ unsigned int hpair(unsigned int u, unsigned int v) {
  return pk2(lrelu(bflo(u) + bflo(v)), lrelu(bfhi(u) + bfhi(v)));
}

// ---- transpose+convert: W (K x 256, f32) -> Wt (256 x K, bf16)
__global__ __launch_bounds__(256) void transpose_k(const float* __restrict__ W,
                                                   bf16* __restrict__ Wt, int K)
{
  __shared__ float tile[64][65];
  const int kb = blockIdx.x * 64;
  const int nb = blockIdx.y * 64;
  const int t = threadIdx.x;
  #pragma unroll
  for (int i = 0; i < 16; ++i) {
    int idx = t + 256 * i;
    int r = idx >> 6, c = idx & 63;
    tile[r][c] = W[(size_t)(kb + r) * 256 + nb + c];
  }
  __syncthreads();
  #pragma unroll
  for (int i = 0; i < 16; ++i) {
    int idx = t + 256 * i;
    int r = idx >> 6, c = idx & 63;
    Wt[(size_t)(nb + r) * K + kb + c] = __float2bfloat16(tile[c][r]);
  }
}

// ---- uv_kernel: hero/board (VALU) + hidden GEMM with LDS-staged hWt.
//      UV[item][row 0..5]=U_p (no bias), [6..15]=V_b + biasH. 4 items/block.
__global__ __launch_bounds__(256) void uv_kernel(
    const int* __restrict__ x, const float* __restrict__ card_emb,
    const float* __restrict__ hand_W, const float* __restrict__ hand_b,
    const float* __restrict__ board_W, const float* __restrict__ board_b,
    const bf16* __restrict__ hWt, const float* __restrict__ hidden_b,
    bf16* __restrict__ UV)
{
  static constexpr int H0[6] = {0,0,0,1,1,2};
  static constexpr int H1[6] = {1,2,3,2,3,3};
  static constexpr int B0[10] = {0,0,0,0,0,0,1,1,1,2};
  static constexpr int B1[10] = {1,1,1,2,2,3,2,2,3,3};
  static constexpr int B2[10] = {2,3,4,3,4,4,3,4,4,4};

  __shared__ bf16 A[4][16][264];    // rows 0..5=[hero|0], 6..15=[0|board]
  __shared__ bf16 Bst[64 * 256];    // one 64-row quarter of hWt, xor-swizzled
  __shared__ float emb[4][9][16];
  __shared__ float biasH[256];

  const int t = threadIdx.x;
  const int w = t >> 6, l = t & 63;
  const int item = blockIdx.x * 4 + w;

  biasH[t] = hidden_b[t];

  // embeddings (wave-local)
  for (int idx = l; idx < 144; idx += 64) {
    int ci = idx >> 4, e = idx & 15;
    int rk = x[item * 18 + 2 * ci], st = x[item * 18 + 2 * ci + 1];
    int card = (rk > 0 ? rk - 1 : 0) + (st > 0 ? (st - 1) * 13 : 0);
    emb[w][ci][e] = card_emb[card * 16 + e];
  }
  #pragma unroll
  for (int p = 0; p < 6; ++p) *(unsigned int*)&A[w][p][128 + 2 * l] = 0u;
  #pragma unroll
  for (int b = 0; b < 10; ++b) *(unsigned int*)&A[w][6 + b][2 * l] = 0u;

  // hero (6x128) + board (10x128), 2 cols/lane
  #pragma unroll
  for (int jj = 0; jj < 2; ++jj) {
    const int j = jj * 64 + l;
    float wh[32], wb[48];
    #pragma unroll
    for (int k = 0; k < 32; ++k) wh[k] = hand_W[k * 128 + j];
    #pragma unroll
    for (int k = 0; k < 48; ++k) wb[k] = board_W[k * 128 + j];
    float aH[6], aB[10];
    {
      float hb = hand_b[j], bb = board_b[j];
      #pragma unroll
      for (int p = 0; p < 6; ++p) aH[p] = hb;
      #pragma unroll
      for (int b = 0; b < 10; ++b) aB[b] = bb;
    }
    #pragma unroll
    for (int k = 0; k < 16; ++k) {
      float e[9];
      #pragma unroll
      for (int c = 0; c < 9; ++c) e[c] = emb[w][c][k];
      #pragma unroll
      for (int p = 0; p < 6; ++p)
        aH[p] += e[H0[p]] * wh[k] + e[H1[p]] * wh[16 + k];
      #pragma unroll
      for (int b = 0; b < 10; ++b)
        aB[b] += e[4 + B0[b]] * wb[k] + e[4 + B1[b]] * wb[16 + k] + e[4 + B2[b]] * wb[32 + k];
    }
    #pragma unroll
    for (int p = 0; p < 6; ++p) A[w][p][j] = __float2bfloat16(lrelu(aH[p]));
    #pragma unroll
    for (int b = 0; b < 10; ++b) A[w][6 + b][128 + j] = __float2bfloat16(lrelu(aB[b]));
  }

  // hidden GEMM in 4 N-quarters: D(16x64) per wave per quarter
  const int lr = l & 15, quad = l >> 4;
  bf16* dst = UV + (size_t)item * 4096;

  for (int q = 0; q < 4; ++q) {
    __syncthreads();
    {  // stage hWt rows [64q, 64q+64), all 256 k, xor-swizzled 16B chunks
      const int row = t >> 2, j0 = t & 3;
      const bf16* src = hWt + (size_t)(64 * q + row) * 256;
      #pragma unroll
      for (int c = 0; c < 8; ++c) {
        int j = j0 + 4 * c;                       // chunk 0..31
        short8 v = *(const short8*)(src + j * 8);
        int jp = (j & ~7) | ((j & 7) ^ (row & 7));
        *(short8*)&Bst[row * 256 + jp * 8] = v;
      }
    }
    __syncthreads();

    floatx4 acc[4];
    floatx4 zero = {0.f, 0.f, 0.f, 0.f};
    #pragma unroll
    for (int i = 0; i < 4; ++i) acc[i] = zero;

    #pragma unroll
    for (int ks = 0; ks < 8; ++ks) {
      short8 a = *(const short8*)&A[w][lr][ks * 32 + quad * 8];
      #pragma unroll
      for (int tl = 0; tl < 4; ++tl) {
        int row = 16 * tl + lr;
        int j = 4 * ks + quad;
        int jp = (j & ~7) | ((j & 7) ^ (row & 7));
        short8 b = *(const short8*)&Bst[row * 256 + jp * 8];
        acc[tl] = __builtin_amdgcn_mfma_f32_16x16x32_bf16(a, b, acc[tl], 0, 0, 0);
      }
    }

    #pragma unroll
    for (int tl = 0; tl < 4; ++tl) {
      int n = 64 * q + 16 * tl + lr;
      float bn = biasH[n];
      #pragma unroll
      for (int r = 0; r < 4; ++r) {
        int m = quad * 4 + r;
        float v = acc[tl][r] + (m >= 6 ? bn : 0.f);   // fold bias into V rows
        dst[m * 256 + n] = __float2bfloat16(v);
      }
    }
  }
}

// ---- out GEMM, split-K, As built on the fly from UV (h never materialized)
__global__ __launch_bounds__(256) void out_gemm(
    const bf16* __restrict__ UV, const bf16* __restrict__ Wt,
    float* __restrict__ pbuf)
{
  __shared__ bf16 As[64 * 64];
  __shared__ bf16 Bs[256 * 64];

  const int t = threadIdx.x;
  const int w = t >> 6, l = t & 63, lr = l & 15, quad = l >> 4;
  const int m0 = blockIdx.x * 64;
  const int ks0 = blockIdx.y * KSLICE;

  const int ar = t >> 2;            // As row (item within tile)
  const int ac = t & 3;             // 16-col group
  const bf16* bS = Wt + (size_t)t * KO + ks0;   // Bs row n = t

  floatx4 acc[16];
  floatx4 zero = {0.f, 0.f, 0.f, 0.f};
  #pragma unroll
  for (int i = 0; i < 16; ++i) acc[i] = zero;

  for (int it = 0; it < KSLICE / 64; ++it) {
    const int gk = ks0 + it * 64;
    const int combo = gk >> 8;                    // wave-uniform
    const int urow = combo / 10, vrow = 6 + combo % 10;
    const int c0 = gk & 255;

    const bf16* ub = UV + ((size_t)(m0 + ar) * 16 + urow) * 256 + c0 + ac * 16;
    const bf16* vb = UV + ((size_t)(m0 + ar) * 16 + vrow) * 256 + c0 + ac * 16;
    uint4 uu0 = *(const uint4*)ub;
    uint4 uu1 = *(const uint4*)(ub + 8);
    uint4 vv0 = *(const uint4*)vb;
    uint4 vv1 = *(const uint4*)(vb + 8);
    uint4 bvals[8];
    #pragma unroll
    for (int j = 0; j < 8; ++j)
      bvals[j] = *(const uint4*)(bS + it * 64 + j * 8);

    __syncthreads();   // prior iter's frag reads done

    uint4 h0, h1;
    h0.x = hpair(uu0.x, vv0.x); h0.y = hpair(uu0.y, vv0.y);
    h0.z = hpair(uu0.z, vv0.z); h0.w = hpair(uu0.w, vv0.w);
    h1.x = hpair(uu1.x, vv1.x); h1.y = hpair(uu1.y, vv1.y);
    h1.z = hpair(uu1.z, vv1.z); h1.w = hpair(uu1.w, vv1.w);
    {
      int jA0 = (2 * ac) ^ (ar & 7);
      int jA1 = (2 * ac + 1) ^ (ar & 7);
      *(uint4*)&As[ar * 64 + jA0 * 8] = h0;
      *(uint4*)&As[ar * 64 + jA1 * 8] = h1;
    }
    #pragma unroll
    for (int j = 0; j < 8; ++j) {
      int jp = j ^ (t & 7);
      *(uint4*)&Bs[t * 64 + jp * 8] = bvals[j];
    }
    __syncthreads();

    #pragma unroll
    for (int ks = 0; ks < 2; ++ks) {
      short8 af[4], bfr[4];
      #pragma unroll
      for (int i = 0; i < 4; ++i) {
        int row = i * 16 + lr;
        int jp = (4 * ks + quad) ^ (row & 7);
        af[i] = *(const short8*)&As[row * 64 + jp * 8];
      }
      #pragma unroll
      for (int j = 0; j < 4; ++j) {
        int row = w * 64 + j * 16 + lr;
        int jp = (4 * ks + quad) ^ (row & 7);
        bfr[j] = *(const short8*)&Bs[row * 64 + jp * 8];
      }
      #pragma unroll
      for (int i = 0; i < 4; ++i)
        #pragma unroll
        for (int j = 0; j < 4; ++j)
          acc[i * 4 + j] = __builtin_amdgcn_mfma_f32_16x16x32_bf16(af[i], bfr[j], acc[i * 4 + j], 0, 0, 0);
    }
  }

  float* dst = pbuf + (size_t)blockIdx.y * 3072 * 256;
  #pragma unroll
  for (int i = 0; i < 4; ++i)
    #pragma unroll
    for (int tl = 0; tl < 4; ++tl) {
      int n = w * 64 + tl * 16 + lr;
      #pragma unroll
      for (int r = 0; r < 4; ++r) {
        int m = m0 + i * 16 + quad * 4 + r;
        dst[(size_t)m * 256 + n] = acc[i * 4 + tl][r];
      }
    }
}

// ---- reduce split-K partials + bias + lrelu
__global__ __launch_bounds__(256) void reduce_bias(
    const float* __restrict__ pbuf, const float* __restrict__ outb,
    float* __restrict__ out, int n4tot)
{
  int idx = blockIdx.x * 256 + threadIdx.x;       // one float4
  if (idx >= n4tot) return;
  const float4* p4 = (const float4*)pbuf;
  float4 s = p4[idx];
  #pragma unroll
  for (int k = 1; k < KS; ++k) {
    float4 v = p4[idx + (size_t)k * n4tot];
    s.x += v.x; s.y += v.y; s.z += v.z; s.w += v.w;
  }
  int n4 = (idx & 63) * 4;
  float4 b = *(const float4*)&outb[n4];
  float4 r;
  r.x = lrelu(s.x + b.x); r.y = lrelu(s.y + b.y);
  r.z = lrelu(s.z + b.z); r.w = lrelu(s.w + b.w);
  ((float4*)out)[idx] = r;
}

extern "C" void kernel_launch(void* const* d_in, const int* in_sizes, int n_in,
                              void* d_out, int out_size, void* d_ws, size_t ws_size,
                              hipStream_t stream)
{
  const int*   x        = (const int*)  d_in[0];
  const float* card_emb = (const float*)d_in[1];
  const float* hand_W   = (const float*)d_in[2];
  const float* hand_b   = (const float*)d_in[3];
  const float* board_W  = (const float*)d_in[4];
  const float* board_b  = (const float*)d_in[5];
  const float* hidden_W = (const float*)d_in[6];
  const float* hidden_b = (const float*)d_in[7];
  const float* out_W    = (const float*)d_in[8];
  const float* out_b    = (const float*)d_in[9];
  float* out = (float*)d_out;

  const int NI = in_sizes[0] / 18;   // 3072 items

  char* ws = (char*)d_ws;
  bf16* hWt = (bf16*)ws;                                   // 256*256*2      = 128 KB
  bf16* oWt = (bf16*)(ws + 131072);                        // 256*15360*2    = 7.5 MB
  bf16* UV  = (bf16*)(ws + 131072 + 7864320);              // NI*16*256*2    = 24 MB
  float* pbuf = (float*)(ws + 131072 + 7864320 + (size_t)NI * 4096 * 2);  // KS*NI*256*4

  transpose_k<<<dim3(4, 4),   256, 0, stream>>>(hidden_W, hWt, 256);
  transpose_k<<<dim3(240, 4), 256, 0, stream>>>(out_W,    oWt, KO);
  uv_kernel<<<NI / 4, 256, 0, stream>>>(x, card_emb, hand_W, hand_b,
                                        board_W, board_b, hWt, hidden_b, UV);
  out_gemm<<<dim3(NI / 64, KS), 256, 0, stream>>>(UV, oWt, pbuf);
  const int n4tot = NI * 256 / 4;
  reduce_bias<<<(n4tot + 255) / 256, 256, 0, stream>>>(pbuf, out_b, out, n4tot);
}

// Round 6
// 289.245 us; speedup vs baseline: 1.1072x; 1.1072x over previous
//
#include <hip/hip_runtime.h>
#include <hip/hip_bf16.h>
#include <cstdint>
#include <cstddef>

typedef __hip_bfloat16 bf16;
typedef __attribute__((ext_vector_type(8))) short short8;
typedef __attribute__((ext_vector_type(4))) float floatx4;

#define KO 15360
#define KS 12
#define KSLICE 1280   /* KO / KS, multiple of 256 */

__device__ __forceinline__ float lrelu(float v) { return v > 0.f ? v : 0.01f * v; }

__device__ __forceinline__ float bflo(unsigned int u) {
  unsigned int x = u << 16; float f; __builtin_memcpy(&f, &x, 4); return f;
}
__device__ __forceinline__ float bfhi(unsigned int u) {
  unsigned int x = u & 0xffff0000u; float f; __builtin_memcpy(&f, &x, 4); return f;
}
__device__ __forceinline__ unsigned int pk2(float lo, float hi) {
  bf16 a = __float2bfloat16(lo), b = __float2bfloat16(hi);
  unsigned short ua, ub;
  __builtin_memcpy(&ua, &a, 2); __builtin_memcpy(&ub, &b, 2);
  return (unsigned int)ua | ((unsigned int)ub << 16);
}
__device__ __forceinline__ unsigned int hpair(unsigned int u, unsigned int v) {
  return pk2(lrelu(bflo(u) + bflo(v)), lrelu(bfhi(u) + bfhi(v)));
}

// ---- transpose+convert: W (K x 256, f32) -> Wt (256 x K, bf16)
__global__ __launch_bounds__(256) void transpose_k(const float* __restrict__ W,
                                                   bf16* __restrict__ Wt, int K)
{
  __shared__ float tile[64][65];
  const int kb = blockIdx.x * 64;
  const int nb = blockIdx.y * 64;
  const int t = threadIdx.x;
  #pragma unroll
  for (int i = 0; i < 16; ++i) {
    int idx = t + 256 * i;
    int r = idx >> 6, c = idx & 63;
    tile[r][c] = W[(size_t)(kb + r) * 256 + nb + c];
  }
  __syncthreads();
  #pragma unroll
  for (int i = 0; i < 16; ++i) {
    int idx = t + 256 * i;
    int r = idx >> 6, c = idx & 63;
    Wt[(size_t)(nb + r) * K + kb + c] = __float2bfloat16(tile[c][r]);
  }
}

// ---- K1: hero/board layers -> A matrices in MFMA-frag-packed layout.
//      Abuf[item] = 4096 bf16; chunk c (16B) = {ks=c>>6, lane=c&63}:
//      holds A[m=lane&15][ks*32 + (lane>>4)*8 + 0..7].  2 items/block.
__global__ __launch_bounds__(256) void hb_pack(
    const int* __restrict__ x, const float* __restrict__ card_emb,
    const float* __restrict__ hand_W, const float* __restrict__ hand_b,
    const float* __restrict__ board_W, const float* __restrict__ board_b,
    bf16* __restrict__ Abuf)
{
  static constexpr int H0[6] = {0,0,0,1,1,2};
  static constexpr int H1[6] = {1,2,3,2,3,3};
  static constexpr int B0[10] = {0,0,0,0,0,0,1,1,1,2};
  static constexpr int B1[10] = {1,1,1,2,2,3,2,2,3,3};
  static constexpr int B2[10] = {2,3,4,3,4,4,3,4,4,4};

  __shared__ float wH[32 * 128];
  __shared__ float wB[48 * 128];
  __shared__ float bH[128], bB[128];
  __shared__ float emb[2][9][16];
  __shared__ bf16 At[2][16][264];

  const int t = threadIdx.x;
  const int item0 = blockIdx.x * 2;

  for (int i = t; i < 32 * 128; i += 256) wH[i] = hand_W[i];
  for (int i = t; i < 48 * 128; i += 256) wB[i] = board_W[i];
  if (t < 128) { bH[t] = hand_b[t]; bB[t] = board_b[t]; }
  for (int ii = t; ii < 288; ii += 256) {          // FIX: 288 work items > 256 threads
    int li = ii / 144, idx = ii - li * 144;
    int ci = idx >> 4, e = idx & 15;
    int rk = x[(item0 + li) * 18 + 2 * ci], st = x[(item0 + li) * 18 + 2 * ci + 1];
    int card = (rk > 0 ? rk - 1 : 0) + (st > 0 ? (st - 1) * 13 : 0);
    emb[li][ci][e] = card_emb[card * 16 + e];
  }
  __syncthreads();

  const int li = t >> 7, j = t & 127;
  {
    bf16 z = __float2bfloat16(0.f);
    #pragma unroll
    for (int p = 0; p < 6; ++p) At[li][p][128 + j] = z;
    #pragma unroll
    for (int b = 0; b < 10; ++b) At[li][6 + b][j] = z;
  }
  float aH[6], aB[10];
  {
    float hb = bH[j], bb = bB[j];
    #pragma unroll
    for (int p = 0; p < 6; ++p) aH[p] = hb;
    #pragma unroll
    for (int b = 0; b < 10; ++b) aB[b] = bb;
  }
  #pragma unroll
  for (int k = 0; k < 16; ++k) {
    float e[9];
    #pragma unroll
    for (int c = 0; c < 9; ++c) e[c] = emb[li][c][k];
    float w0 = wH[k * 128 + j], w1 = wH[(16 + k) * 128 + j];
    float v0 = wB[k * 128 + j], v1 = wB[(16 + k) * 128 + j], v2 = wB[(32 + k) * 128 + j];
    #pragma unroll
    for (int p = 0; p < 6; ++p)
      aH[p] += e[H0[p]] * w0 + e[H1[p]] * w1;
    #pragma unroll
    for (int b = 0; b < 10; ++b)
      aB[b] += e[4 + B0[b]] * v0 + e[4 + B1[b]] * v1 + e[4 + B2[b]] * v2;
  }
  #pragma unroll
  for (int p = 0; p < 6; ++p) At[li][p][j] = __float2bfloat16(lrelu(aH[p]));
  #pragma unroll
  for (int b = 0; b < 10; ++b) At[li][6 + b][128 + j] = __float2bfloat16(lrelu(aB[b]));
  __syncthreads();

  // repack to frag order; stores perfectly lane-coalesced
  #pragma unroll
  for (int li2 = 0; li2 < 2; ++li2) {
    #pragma unroll
    for (int cc = 0; cc < 2; ++cc) {
      int c = t + 256 * cc;
      int m = c & 15, kq = (c >> 4) & 3, ks = c >> 6;
      short8 v = *(const short8*)&At[li2][m][ks * 32 + kq * 8];
      *(short8*)(Abuf + (size_t)(item0 + li2) * 4096 + (size_t)c * 8) = v;
    }
  }
}

// ---- K2: hidden GEMM with hWt B-fragments persistent in VGPRs.
//      UV[item][m 0..5]=U_p, [6..15]=V_b + biasH. 6 items/block, 4 waves = n-quarters.
__global__ __launch_bounds__(256) void uv_gemm(
    const bf16* __restrict__ Abuf, const bf16* __restrict__ hWt,
    const float* __restrict__ hidden_b, bf16* __restrict__ UV)
{
  const int t = threadIdx.x, w = t >> 6, l = t & 63;
  const int lr = l & 15, quad = l >> 4;

  short8 bfrag[4][8];
  float bias[4];
  #pragma unroll
  for (int tl = 0; tl < 4; ++tl) {
    int n = w * 64 + tl * 16 + lr;
    bias[tl] = hidden_b[n];
    #pragma unroll
    for (int ks = 0; ks < 8; ++ks)
      bfrag[tl][ks] = *(const short8*)(hWt + (size_t)n * 256 + ks * 32 + quad * 8);
  }

  const int i0 = blockIdx.x * 6;
  for (int ii = 0; ii < 6; ++ii) {
    const bf16* ab = Abuf + (size_t)(i0 + ii) * 4096;
    short8 a[8];
    #pragma unroll
    for (int ks = 0; ks < 8; ++ks)
      a[ks] = *(const short8*)(ab + (size_t)(ks * 64 + l) * 8);

    floatx4 acc[4];
    floatx4 zero = {0.f, 0.f, 0.f, 0.f};
    #pragma unroll
    for (int i = 0; i < 4; ++i) acc[i] = zero;
    #pragma unroll
    for (int ks = 0; ks < 8; ++ks)
      #pragma unroll
      for (int tl = 0; tl < 4; ++tl)
        acc[tl] = __builtin_amdgcn_mfma_f32_16x16x32_bf16(a[ks], bfrag[tl][ks], acc[tl], 0, 0, 0);

    bf16* dst = UV + (size_t)(i0 + ii) * 4096;
    #pragma unroll
    for (int tl = 0; tl < 4; ++tl) {
      int n = w * 64 + tl * 16 + lr;
      #pragma unroll
      for (int r = 0; r < 4; ++r) {
        int m = quad * 4 + r;
        float v = acc[tl][r] + (m >= 6 ? bias[tl] : 0.f);
        dst[m * 256 + n] = __float2bfloat16(v);
      }
    }
  }
}

// ---- K3: out GEMM, split-K, As built on the fly from UV; coalesced everywhere.
__global__ __launch_bounds__(256) void out_gemm(
    const bf16* __restrict__ UV, const bf16* __restrict__ Wt,
    float* __restrict__ pbuf)
{
  __shared__ bf16 As[64 * 64];
  __shared__ bf16 Bs[256 * 64];

  const int t = threadIdx.x;
  const int w = t >> 6, l = t & 63, lr = l & 15, quad = l >> 4;
  const int m0 = blockIdx.x * 64;
  const int ks0 = blockIdx.y * KSLICE;
  const int ar = t >> 2, ac = t & 3;   // staging: row, 16-elem col group

  floatx4 acc[16];
  floatx4 zero = {0.f, 0.f, 0.f, 0.f};
  #pragma unroll
  for (int i = 0; i < 16; ++i) acc[i] = zero;

  for (int it = 0; it < KSLICE / 64; ++it) {
    const int gk = ks0 + it * 64;
    const int combo = gk >> 8;                    // wave-uniform
    const int urow = combo / 10, vrow = 6 + (combo - urow * 10);
    const int c0 = gk & 255;

    const bf16* ub = UV + ((size_t)(m0 + ar) * 16 + urow) * 256 + c0 + ac * 16;
    const bf16* vb = UV + ((size_t)(m0 + ar) * 16 + vrow) * 256 + c0 + ac * 16;
    uint4 uu0 = *(const uint4*)ub;
    uint4 uu1 = *(const uint4*)(ub + 8);
    uint4 vv0 = *(const uint4*)vb;
    uint4 vv1 = *(const uint4*)(vb + 8);
    uint4 bvals[8];
    #pragma unroll
    for (int p = 0; p < 4; ++p) {                 // rows ar, ar+64, ar+128, ar+192
      const bf16* bsrc = Wt + (size_t)(ar + 64 * p) * KO + gk + ac * 16;
      bvals[2 * p]     = *(const uint4*)bsrc;
      bvals[2 * p + 1] = *(const uint4*)(bsrc + 8);
    }

    __syncthreads();   // prior iter's frag reads done

    uint4 h0, h1;
    h0.x = hpair(uu0.x, vv0.x); h0.y = hpair(uu0.y, vv0.y);
    h0.z = hpair(uu0.z, vv0.z); h0.w = hpair(uu0.w, vv0.w);
    h1.x = hpair(uu1.x, vv1.x); h1.y = hpair(uu1.y, vv1.y);
    h1.z = hpair(uu1.z, vv1.z); h1.w = hpair(uu1.w, vv1.w);
    {
      int jA0 = (2 * ac) ^ (ar & 7);
      int jA1 = (2 * ac + 1) ^ (ar & 7);
      *(uint4*)&As[ar * 64 + jA0 * 8] = h0;
      *(uint4*)&As[ar * 64 + jA1 * 8] = h1;
    }
    #pragma unroll
    for (int p = 0; p < 4; ++p) {
      int row = ar + 64 * p;
      int j0 = (2 * ac) ^ (row & 7);
      int j1 = (2 * ac + 1) ^ (row & 7);
      *(uint4*)&Bs[row * 64 + j0 * 8] = bvals[2 * p];
      *(uint4*)&Bs[row * 64 + j1 * 8] = bvals[2 * p + 1];
    }
    __syncthreads();

    #pragma unroll
    for (int ks = 0; ks < 2; ++ks) {
      short8 af[4], bfr[4];
      #pragma unroll
      for (int i = 0; i < 4; ++i) {
        int row = i * 16 + lr;
        int jp = (4 * ks + quad) ^ (row & 7);
        af[i] = *(const short8*)&As[row * 64 + jp * 8];
      }
      #pragma unroll
      for (int j = 0; j < 4; ++j) {
        int row = w * 64 + j * 16 + lr;
        int jp = (4 * ks + quad) ^ (row & 7);
        bfr[j] = *(const short8*)&Bs[row * 64 + jp * 8];
      }
      #pragma unroll
      for (int i = 0; i < 4; ++i)
        #pragma unroll
        for (int j = 0; j < 4; ++j)
          acc[i * 4 + j] = __builtin_amdgcn_mfma_f32_16x16x32_bf16(af[i], bfr[j], acc[i * 4 + j], 0, 0, 0);
    }
  }

  // lane-linear coalesced partial store: [by][bx][w][q][l]
  float* dst = pbuf + (((size_t)blockIdx.y * 48 + blockIdx.x) * 4 + w) * 4096 + l;
  #pragma unroll
  for (int a = 0; a < 16; ++a)
    #pragma unroll
    for (int r = 0; r < 4; ++r)
      dst[(a * 4 + r) * 64] = acc[a][r];
}

// ---- K4: reduce split-K partials (permuted layout) + bias + lrelu
__global__ __launch_bounds__(256) void reduce_bias(
    const float* __restrict__ pbuf, const float* __restrict__ outb,
    float* __restrict__ out, int slice_stride)
{
  int idx = blockIdx.x * 256 + threadIdx.x;
  float s = 0.f;
  #pragma unroll
  for (int k = 0; k < KS; ++k) s += pbuf[idx + (size_t)k * slice_stride];
  int l = idx & 63, q = (idx >> 6) & 63, w = (idx >> 12) & 3, bx = idx >> 14;
  int a = q >> 2, r = q & 3, i = a >> 2, tl = a & 3;
  int lr = l & 15, quad = l >> 4;
  int m = bx * 64 + i * 16 + quad * 4 + r;
  int n = w * 64 + tl * 16 + lr;
  out[(size_t)m * 256 + n] = lrelu(s + outb[n]);
}

extern "C" void kernel_launch(void* const* d_in, const int* in_sizes, int n_in,
                              void* d_out, int out_size, void* d_ws, size_t ws_size,
                              hipStream_t stream)
{
  const int*   x        = (const int*)  d_in[0];
  const float* card_emb = (const float*)d_in[1];
  const float* hand_W   = (const float*)d_in[2];
  const float* hand_b   = (const float*)d_in[3];
  const float* board_W  = (const float*)d_in[4];
  const float* board_b  = (const float*)d_in[5];
  const float* hidden_W = (const float*)d_in[6];
  const float* hidden_b = (const float*)d_in[7];
  const float* out_W    = (const float*)d_in[8];
  const float* out_b    = (const float*)d_in[9];
  float* out = (float*)d_out;

  const int NI = in_sizes[0] / 18;   // 3072 items

  char* ws = (char*)d_ws;
  bf16* hWt  = (bf16*)ws;                                     // 128 KB
  bf16* oWt  = (bf16*)(ws + 131072);                          // 7.5 MB
  bf16* UV   = (bf16*)(ws + 131072 + 7864320);                // NI*4096*2 = 24 MB
  bf16* Abuf = (bf16*)(ws + 131072 + 7864320 + (size_t)NI * 8192);   // 24 MB
  float* pbuf = (float*)Abuf;   // reuses Abuf (dead after uv_gemm): KS*NI*256*4 = 37.7 MB

  transpose_k<<<dim3(4, 4),   256, 0, stream>>>(hidden_W, hWt, 256);
  transpose_k<<<dim3(240, 4), 256, 0, stream>>>(out_W,    oWt, KO);
  hb_pack<<<NI / 2, 256, 0, stream>>>(x, card_emb, hand_W, hand_b,
                                      board_W, board_b, Abuf);
  uv_gemm<<<NI / 6, 256, 0, stream>>>(Abuf, hWt, hidden_b, UV);
  out_gemm<<<dim3(NI / 64, KS), 256, 0, stream>>>(UV, oWt, pbuf);
  reduce_bias<<<NI, 256, 0, stream>>>(pbuf, out_b, out, NI * 256);
}

// Round 7
// 285.790 us; speedup vs baseline: 1.1206x; 1.0121x over previous
//
#include <hip/hip_runtime.h>
#include <hip/hip_bf16.h>
#include <cstdint>
#include <cstddef>

typedef __hip_bfloat16 bf16;
typedef __attribute__((ext_vector_type(8))) short short8;
typedef __attribute__((ext_vector_type(4))) float floatx4;

#define KO 15360
#define KS 12
#define KSLICE 1280   /* KO / KS, multiple of 256 */

__device__ __forceinline__ float lrelu(float v) { return v > 0.f ? v : 0.01f * v; }

__device__ __forceinline__ float bflo(unsigned int u) {
  unsigned int x = u << 16; float f; __builtin_memcpy(&f, &x, 4); return f;
}
__device__ __forceinline__ float bfhi(unsigned int u) {
  unsigned int x = u & 0xffff0000u; float f; __builtin_memcpy(&f, &x, 4); return f;
}
__device__ __forceinline__ unsigned int pk2(float lo, float hi) {
  bf16 a = __float2bfloat16(lo), b = __float2bfloat16(hi);
  unsigned short ua, ub;
  __builtin_memcpy(&ua, &a, 2); __builtin_memcpy(&ub, &b, 2);
  return (unsigned int)ua | ((unsigned int)ub << 16);
}
__device__ __forceinline__ unsigned int hpair(unsigned int u, unsigned int v) {
  return pk2(lrelu(bflo(u) + bflo(v)), lrelu(bfhi(u) + bfhi(v)));
}

// ---- transpose+convert: W (K x 256, f32) -> Wt (256 x K, bf16)
__global__ __launch_bounds__(256) void transpose_k(const float* __restrict__ W,
                                                   bf16* __restrict__ Wt, int K)
{
  __shared__ float tile[64][65];
  const int kb = blockIdx.x * 64;
  const int nb = blockIdx.y * 64;
  const int t = threadIdx.x;
  #pragma unroll
  for (int i = 0; i < 16; ++i) {
    int idx = t + 256 * i;
    int r = idx >> 6, c = idx & 63;
    tile[r][c] = W[(size_t)(kb + r) * 256 + nb + c];
  }
  __syncthreads();
  #pragma unroll
  for (int i = 0; i < 16; ++i) {
    int idx = t + 256 * i;
    int r = idx >> 6, c = idx & 63;
    Wt[(size_t)(nb + r) * K + kb + c] = __float2bfloat16(tile[c][r]);
  }
}

// ---- K1: hero/board layers -> A matrices in MFMA-frag-packed layout.
//      Abuf[item] = 4096 bf16; chunk c (16B) = {ks=c>>6, lane=c&63}:
//      holds A[m=lane&15][ks*32 + (lane>>4)*8 + 0..7].  4 items/block, 2 passes.
__global__ __launch_bounds__(256) void hb_pack(
    const int* __restrict__ x, const float* __restrict__ card_emb,
    const float* __restrict__ hand_W, const float* __restrict__ hand_b,
    const float* __restrict__ board_W, const float* __restrict__ board_b,
    bf16* __restrict__ Abuf)
{
  static constexpr int H0[6] = {0,0,0,1,1,2};
  static constexpr int H1[6] = {1,2,3,2,3,3};
  static constexpr int B0[10] = {0,0,0,0,0,0,1,1,1,2};
  static constexpr int B1[10] = {1,1,1,2,2,3,2,2,3,3};
  static constexpr int B2[10] = {2,3,4,3,4,4,3,4,4,4};

  __shared__ float wH[32 * 128];
  __shared__ float wB[48 * 128];
  __shared__ float bH[128], bB[128];
  __shared__ float emb[4][9][16];
  __shared__ bf16 At[2][16][264];

  const int t = threadIdx.x;
  const int item0 = blockIdx.x * 4;

  for (int i = t; i < 32 * 128; i += 256) wH[i] = hand_W[i];
  for (int i = t; i < 48 * 128; i += 256) wB[i] = board_W[i];
  if (t < 128) { bH[t] = hand_b[t]; bB[t] = board_b[t]; }
  for (int ii = t; ii < 576; ii += 256) {          // 4 items x 144 entries
    int li = ii / 144, idx = ii - li * 144;
    int ci = idx >> 4, e = idx & 15;
    int rk = x[(item0 + li) * 18 + 2 * ci], st = x[(item0 + li) * 18 + 2 * ci + 1];
    int card = (rk > 0 ? rk - 1 : 0) + (st > 0 ? (st - 1) * 13 : 0);
    emb[li][ci][e] = card_emb[card * 16 + e];
  }
  __syncthreads();

  const int half = t >> 7, j = t & 127;

  for (int pass = 0; pass < 2; ++pass) {
    const int embi = 2 * pass + half;
    {
      bf16 z = __float2bfloat16(0.f);
      #pragma unroll
      for (int p = 0; p < 6; ++p) At[half][p][128 + j] = z;
      #pragma unroll
      for (int b = 0; b < 10; ++b) At[half][6 + b][j] = z;
    }
    float aH[6], aB[10];
    {
      float hb = bH[j], bb = bB[j];
      #pragma unroll
      for (int p = 0; p < 6; ++p) aH[p] = hb;
      #pragma unroll
      for (int b = 0; b < 10; ++b) aB[b] = bb;
    }
    #pragma unroll
    for (int k = 0; k < 16; ++k) {
      float e[9];
      #pragma unroll
      for (int c = 0; c < 9; ++c) e[c] = emb[embi][c][k];
      float w0 = wH[k * 128 + j], w1 = wH[(16 + k) * 128 + j];
      float v0 = wB[k * 128 + j], v1 = wB[(16 + k) * 128 + j], v2 = wB[(32 + k) * 128 + j];
      #pragma unroll
      for (int p = 0; p < 6; ++p)
        aH[p] += e[H0[p]] * w0 + e[H1[p]] * w1;
      #pragma unroll
      for (int b = 0; b < 10; ++b)
        aB[b] += e[4 + B0[b]] * v0 + e[4 + B1[b]] * v1 + e[4 + B2[b]] * v2;
    }
    #pragma unroll
    for (int p = 0; p < 6; ++p) At[half][p][j] = __float2bfloat16(lrelu(aH[p]));
    #pragma unroll
    for (int b = 0; b < 10; ++b) At[half][6 + b][128 + j] = __float2bfloat16(lrelu(aB[b]));
    __syncthreads();

    // repack this pass's two items to frag order; lane-coalesced stores
    #pragma unroll
    for (int li2 = 0; li2 < 2; ++li2) {
      #pragma unroll
      for (int cc = 0; cc < 2; ++cc) {
        int c = t + 256 * cc;
        int m = c & 15, kq = (c >> 4) & 3, ks = c >> 6;
        short8 v = *(const short8*)&At[li2][m][ks * 32 + kq * 8];
        *(short8*)(Abuf + (size_t)(item0 + 2 * pass + li2) * 4096 + (size_t)c * 8) = v;
      }
    }
    __syncthreads();   // At reused next pass
  }
}

// ---- K2: hidden GEMM with hWt B-fragments persistent in VGPRs.
//      UV[item][m 0..5]=U_p, [6..15]=V_b + biasH. 6 items/block, 4 waves = n-quarters.
__global__ __launch_bounds__(256, 2) void uv_gemm(
    const bf16* __restrict__ Abuf, const bf16* __restrict__ hWt,
    const float* __restrict__ hidden_b, bf16* __restrict__ UV)
{
  const int t = threadIdx.x, w = t >> 6, l = t & 63;
  const int lr = l & 15, quad = l >> 4;

  short8 bfrag[4][8];
  float bias[4];
  #pragma unroll
  for (int tl = 0; tl < 4; ++tl) {
    int n = w * 64 + tl * 16 + lr;
    bias[tl] = hidden_b[n];
    #pragma unroll
    for (int ks = 0; ks < 8; ++ks)
      bfrag[tl][ks] = *(const short8*)(hWt + (size_t)n * 256 + ks * 32 + quad * 8);
  }

  const int i0 = blockIdx.x * 6;
  for (int ii = 0; ii < 6; ++ii) {
    const bf16* ab = Abuf + (size_t)(i0 + ii) * 4096;
    short8 a[8];
    #pragma unroll
    for (int ks = 0; ks < 8; ++ks)
      a[ks] = *(const short8*)(ab + (size_t)(ks * 64 + l) * 8);

    floatx4 acc[4];
    floatx4 zero = {0.f, 0.f, 0.f, 0.f};
    #pragma unroll
    for (int i = 0; i < 4; ++i) acc[i] = zero;
    #pragma unroll
    for (int ks = 0; ks < 8; ++ks)
      #pragma unroll
      for (int tl = 0; tl < 4; ++tl)
        acc[tl] = __builtin_amdgcn_mfma_f32_16x16x32_bf16(a[ks], bfrag[tl][ks], acc[tl], 0, 0, 0);

    bf16* dst = UV + (size_t)(i0 + ii) * 4096;
    #pragma unroll
    for (int tl = 0; tl < 4; ++tl) {
      int n = w * 64 + tl * 16 + lr;
      #pragma unroll
      for (int r = 0; r < 4; ++r) {
        int m = quad * 4 + r;
        float v = acc[tl][r] + (m >= 6 ? bias[tl] : 0.f);
        dst[m * 256 + n] = __float2bfloat16(v);
      }
    }
  }
}

// ---- K3: out GEMM, split-K, As built on the fly from UV; coalesced everywhere.
__global__ __launch_bounds__(256, 2) void out_gemm(
    const bf16* __restrict__ UV, const bf16* __restrict__ Wt,
    float* __restrict__ pbuf)
{
  __shared__ bf16 As[64 * 64];
  __shared__ bf16 Bs[256 * 64];

  const int t = threadIdx.x;
  const int w = t >> 6, l = t & 63, lr = l & 15, quad = l >> 4;
  const int m0 = blockIdx.x * 64;
  const int ks0 = blockIdx.y * KSLICE;
  const int ar = t >> 2, ac = t & 3;   // staging: row, 16-elem col group

  floatx4 acc[16];
  floatx4 zero = {0.f, 0.f, 0.f, 0.f};
  #pragma unroll
  for (int i = 0; i < 16; ++i) acc[i] = zero;

  for (int it = 0; it < KSLICE / 64; ++it) {
    const int gk = ks0 + it * 64;
    const int combo = gk >> 8;                    // wave-uniform
    const int urow = combo / 10, vrow = 6 + (combo - urow * 10);
    const int c0 = gk & 255;

    const bf16* ub = UV + ((size_t)(m0 + ar) * 16 + urow) * 256 + c0 + ac * 16;
    const bf16* vb = UV + ((size_t)(m0 + ar) * 16 + vrow) * 256 + c0 + ac * 16;
    uint4 uu0 = *(const uint4*)ub;
    uint4 uu1 = *(const uint4*)(ub + 8);
    uint4 vv0 = *(const uint4*)vb;
    uint4 vv1 = *(const uint4*)(vb + 8);
    uint4 bvals[8];
    #pragma unroll
    for (int p = 0; p < 4; ++p) {                 // rows ar, ar+64, ar+128, ar+192
      const bf16* bsrc = Wt + (size_t)(ar + 64 * p) * KO + gk + ac * 16;
      bvals[2 * p]     = *(const uint4*)bsrc;
      bvals[2 * p + 1] = *(const uint4*)(bsrc + 8);
    }

    __syncthreads();   // prior iter's frag reads done

    uint4 h0, h1;
    h0.x = hpair(uu0.x, vv0.x); h0.y = hpair(uu0.y, vv0.y);
    h0.z = hpair(uu0.z, vv0.z); h0.w = hpair(uu0.w, vv0.w);
    h1.x = hpair(uu1.x, vv1.x); h1.y = hpair(uu1.y, vv1.y);
    h1.z = hpair(uu1.z, vv1.z); h1.w = hpair(uu1.w, vv1.w);
    {
      int jA0 = (2 * ac) ^ (ar & 7);
      int jA1 = (2 * ac + 1) ^ (ar & 7);
      *(uint4*)&As[ar * 64 + jA0 * 8] = h0;
      *(uint4*)&As[ar * 64 + jA1 * 8] = h1;
    }
    #pragma unroll
    for (int p = 0; p < 4; ++p) {
      int row = ar + 64 * p;
      int j0 = (2 * ac) ^ (row & 7);
      int j1 = (2 * ac + 1) ^ (row & 7);
      *(uint4*)&Bs[row * 64 + j0 * 8] = bvals[2 * p];
      *(uint4*)&Bs[row * 64 + j1 * 8] = bvals[2 * p + 1];
    }
    __syncthreads();

    #pragma unroll
    for (int ks = 0; ks < 2; ++ks) {
      short8 af[4], bfr[4];
      #pragma unroll
      for (int i = 0; i < 4; ++i) {
        int row = i * 16 + lr;
        int jp = (4 * ks + quad) ^ (row & 7);
        af[i] = *(const short8*)&As[row * 64 + jp * 8];
      }
      #pragma unroll
      for (int j = 0; j < 4; ++j) {
        int row = w * 64 + j * 16 + lr;
        int jp = (4 * ks + quad) ^ (row & 7);
        bfr[j] = *(const short8*)&Bs[row * 64 + jp * 8];
      }
      #pragma unroll
      for (int i = 0; i < 4; ++i)
        #pragma unroll
        for (int j = 0; j < 4; ++j)
          acc[i * 4 + j] = __builtin_amdgcn_mfma_f32_16x16x32_bf16(af[i], bfr[j], acc[i * 4 + j], 0, 0, 0);
    }
  }

  // lane-linear coalesced partial store: [by][bx][w][q][l]
  float* dst = pbuf + (((size_t)blockIdx.y * 48 + blockIdx.x) * 4 + w) * 4096 + l;
  #pragma unroll
  for (int a = 0; a < 16; ++a)
    #pragma unroll
    for (int r = 0; r < 4; ++r)
      dst[(a * 4 + r) * 64] = acc[a][r];
}

// ---- K4: reduce split-K partials (permuted layout) + bias + lrelu
__global__ __launch_bounds__(256) void reduce_bias(
    const float* __restrict__ pbuf, const float* __restrict__ outb,
    float* __restrict__ out, int slice_stride)
{
  int idx = blockIdx.x * 256 + threadIdx.x;
  float s = 0.f;
  #pragma unroll
  for (int k = 0; k < KS; ++k) s += pbuf[idx + (size_t)k * slice_stride];
  int l = idx & 63, q = (idx >> 6) & 63, w = (idx >> 12) & 3, bx = idx >> 14;
  int a = q >> 2, r = q & 3, i = a >> 2, tl = a & 3;
  int lr = l & 15, quad = l >> 4;
  int m = bx * 64 + i * 16 + quad * 4 + r;
  int n = w * 64 + tl * 16 + lr;
  out[(size_t)m * 256 + n] = lrelu(s + outb[n]);
}

extern "C" void kernel_launch(void* const* d_in, const int* in_sizes, int n_in,
                              void* d_out, int out_size, void* d_ws, size_t ws_size,
                              hipStream_t stream)
{
  const int*   x        = (const int*)  d_in[0];
  const float* card_emb = (const float*)d_in[1];
  const float* hand_W   = (const float*)d_in[2];
  const float* hand_b   = (const float*)d_in[3];
  const float* board_W  = (const float*)d_in[4];
  const float* board_b  = (const float*)d_in[5];
  const float* hidden_W = (const float*)d_in[6];
  const float* hidden_b = (const float*)d_in[7];
  const float* out_W    = (const float*)d_in[8];
  const float* out_b    = (const float*)d_in[9];
  float* out = (float*)d_out;

  const int NI = in_sizes[0] / 18;   // 3072 items

  char* ws = (char*)d_ws;
  bf16* hWt  = (bf16*)ws;                                     // 128 KB
  bf16* oWt  = (bf16*)(ws + 131072);                          // 7.5 MB
  bf16* UV   = (bf16*)(ws + 131072 + 7864320);                // NI*4096*2 = 24 MB
  bf16* Abuf = (bf16*)(ws + 131072 + 7864320 + (size_t)NI * 8192);   // 24 MB
  float* pbuf = (float*)Abuf;   // reuses Abuf (dead after uv_gemm): KS*NI*256*4 = 37.7 MB

  transpose_k<<<dim3(4, 4),   256, 0, stream>>>(hidden_W, hWt, 256);
  transpose_k<<<dim3(240, 4), 256, 0, stream>>>(out_W,    oWt, KO);
  hb_pack<<<NI / 4, 256, 0, stream>>>(x, card_emb, hand_W, hand_b,
                                      board_W, board_b, Abuf);
  uv_gemm<<<NI / 6, 256, 0, stream>>>(Abuf, hWt, hidden_b, UV);
  out_gemm<<<dim3(NI / 64, KS), 256, 0, stream>>>(UV, oWt, pbuf);
  reduce_bias<<<NI, 256, 0, stream>>>(pbuf, out_b, out, NI * 256);
}

// Round 8
// 180.728 us; speedup vs baseline: 1.7720x; 1.5813x over previous
//
#include <hip/hip_runtime.h>
#include <hip/hip_bf16.h>
#include <cstdint>
#include <cstddef>

typedef __hip_bfloat16 bf16;
typedef __attribute__((ext_vector_type(8))) short short8;
typedef __attribute__((ext_vector_type(4))) float floatx4;

#define KO 15360
#define KS 12
#define KSLICE 1280   /* KO / KS, multiple of 256 */

__device__ __forceinline__ float lrelu(float v) { return v > 0.f ? v : 0.01f * v; }

__device__ __forceinline__ float bflo(unsigned int u) {
  unsigned int x = u << 16; float f; __builtin_memcpy(&f, &x, 4); return f;
}
__device__ __forceinline__ float bfhi(unsigned int u) {
  unsigned int x = u & 0xffff0000u; float f; __builtin_memcpy(&f, &x, 4); return f;
}
__device__ __forceinline__ unsigned int pk2(float lo, float hi) {
  bf16 a = __float2bfloat16(lo), b = __float2bfloat16(hi);
  unsigned short ua, ub;
  __builtin_memcpy(&ua, &a, 2); __builtin_memcpy(&ub, &b, 2);
  return (unsigned int)ua | ((unsigned int)ub << 16);
}
__device__ __forceinline__ unsigned int hpair(unsigned int u, unsigned int v) {
  return pk2(lrelu(bflo(u) + bflo(v)), lrelu(bfhi(u) + bfhi(v)));
}

// async 16B global -> LDS (no VGPR round-trip; LDS dest = wave-uniform base + lane*16)
__device__ __forceinline__ void async_lds16(const bf16* g, bf16* l) {
  __builtin_amdgcn_global_load_lds((__attribute__((address_space(1))) void*)(g),
                                   (__attribute__((address_space(3))) void*)(l),
                                   16, 0, 0);
}

// ---- transpose+convert: W (K x 256, f32) -> Wt (256 x K, bf16)
__global__ __launch_bounds__(256) void transpose_k(const float* __restrict__ W,
                                                   bf16* __restrict__ Wt, int K)
{
  __shared__ float tile[64][65];
  const int kb = blockIdx.x * 64;
  const int nb = blockIdx.y * 64;
  const int t = threadIdx.x;
  #pragma unroll
  for (int i = 0; i < 16; ++i) {
    int idx = t + 256 * i;
    int r = idx >> 6, c = idx & 63;
    tile[r][c] = W[(size_t)(kb + r) * 256 + nb + c];
  }
  __syncthreads();
  #pragma unroll
  for (int i = 0; i < 16; ++i) {
    int idx = t + 256 * i;
    int r = idx >> 6, c = idx & 63;
    Wt[(size_t)(nb + r) * K + kb + c] = __float2bfloat16(tile[c][r]);
  }
}

// ---- K1: hero/board layers -> A matrices in MFMA-frag-packed layout.
__global__ __launch_bounds__(256) void hb_pack(
    const int* __restrict__ x, const float* __restrict__ card_emb,
    const float* __restrict__ hand_W, const float* __restrict__ hand_b,
    const float* __restrict__ board_W, const float* __restrict__ board_b,
    bf16* __restrict__ Abuf)
{
  static constexpr int H0[6] = {0,0,0,1,1,2};
  static constexpr int H1[6] = {1,2,3,2,3,3};
  static constexpr int B0[10] = {0,0,0,0,0,0,1,1,1,2};
  static constexpr int B1[10] = {1,1,1,2,2,3,2,2,3,3};
  static constexpr int B2[10] = {2,3,4,3,4,4,3,4,4,4};

  __shared__ float wH[32 * 128];
  __shared__ float wB[48 * 128];
  __shared__ float bH[128], bB[128];
  __shared__ float emb[4][9][16];
  __shared__ bf16 At[2][16][264];

  const int t = threadIdx.x;
  const int item0 = blockIdx.x * 4;

  for (int i = t; i < 32 * 128; i += 256) wH[i] = hand_W[i];
  for (int i = t; i < 48 * 128; i += 256) wB[i] = board_W[i];
  if (t < 128) { bH[t] = hand_b[t]; bB[t] = board_b[t]; }
  for (int ii = t; ii < 576; ii += 256) {
    int li = ii / 144, idx = ii - li * 144;
    int ci = idx >> 4, e = idx & 15;
    int rk = x[(item0 + li) * 18 + 2 * ci], st = x[(item0 + li) * 18 + 2 * ci + 1];
    int card = (rk > 0 ? rk - 1 : 0) + (st > 0 ? (st - 1) * 13 : 0);
    emb[li][ci][e] = card_emb[card * 16 + e];
  }
  __syncthreads();

  const int half = t >> 7, j = t & 127;

  for (int pass = 0; pass < 2; ++pass) {
    const int embi = 2 * pass + half;
    {
      bf16 z = __float2bfloat16(0.f);
      #pragma unroll
      for (int p = 0; p < 6; ++p) At[half][p][128 + j] = z;
      #pragma unroll
      for (int b = 0; b < 10; ++b) At[half][6 + b][j] = z;
    }
    float aH[6], aB[10];
    {
      float hb = bH[j], bb = bB[j];
      #pragma unroll
      for (int p = 0; p < 6; ++p) aH[p] = hb;
      #pragma unroll
      for (int b = 0; b < 10; ++b) aB[b] = bb;
    }
    #pragma unroll
    for (int k = 0; k < 16; ++k) {
      float e[9];
      #pragma unroll
      for (int c = 0; c < 9; ++c) e[c] = emb[embi][c][k];
      float w0 = wH[k * 128 + j], w1 = wH[(16 + k) * 128 + j];
      float v0 = wB[k * 128 + j], v1 = wB[(16 + k) * 128 + j], v2 = wB[(32 + k) * 128 + j];
      #pragma unroll
      for (int p = 0; p < 6; ++p)
        aH[p] += e[H0[p]] * w0 + e[H1[p]] * w1;
      #pragma unroll
      for (int b = 0; b < 10; ++b)
        aB[b] += e[4 + B0[b]] * v0 + e[4 + B1[b]] * v1 + e[4 + B2[b]] * v2;
    }
    #pragma unroll
    for (int p = 0; p < 6; ++p) At[half][p][j] = __float2bfloat16(lrelu(aH[p]));
    #pragma unroll
    for (int b = 0; b < 10; ++b) At[half][6 + b][128 + j] = __float2bfloat16(lrelu(aB[b]));
    __syncthreads();

    #pragma unroll
    for (int li2 = 0; li2 < 2; ++li2) {
      #pragma unroll
      for (int cc = 0; cc < 2; ++cc) {
        int c = t + 256 * cc;
        int m = c & 15, kq = (c >> 4) & 3, ks = c >> 6;
        short8 v = *(const short8*)&At[li2][m][ks * 32 + kq * 8];
        *(short8*)(Abuf + (size_t)(item0 + 2 * pass + li2) * 4096 + (size_t)c * 8) = v;
      }
    }
    __syncthreads();
  }
}

// ---- K2: hidden GEMM with hWt B-fragments persistent in VGPRs.
__global__ __launch_bounds__(256, 2) void uv_gemm(
    const bf16* __restrict__ Abuf, const bf16* __restrict__ hWt,
    const float* __restrict__ hidden_b, bf16* __restrict__ UV)
{
  const int t = threadIdx.x, w = t >> 6, l = t & 63;
  const int lr = l & 15, quad = l >> 4;

  short8 bfrag[4][8];
  float bias[4];
  #pragma unroll
  for (int tl = 0; tl < 4; ++tl) {
    int n = w * 64 + tl * 16 + lr;
    bias[tl] = hidden_b[n];
    #pragma unroll
    for (int ks = 0; ks < 8; ++ks)
      bfrag[tl][ks] = *(const short8*)(hWt + (size_t)n * 256 + ks * 32 + quad * 8);
  }

  const int i0 = blockIdx.x * 6;
  for (int ii = 0; ii < 6; ++ii) {
    const bf16* ab = Abuf + (size_t)(i0 + ii) * 4096;
    short8 a[8];
    #pragma unroll
    for (int ks = 0; ks < 8; ++ks)
      a[ks] = *(const short8*)(ab + (size_t)(ks * 64 + l) * 8);

    floatx4 acc[4];
    floatx4 zero = {0.f, 0.f, 0.f, 0.f};
    #pragma unroll
    for (int i = 0; i < 4; ++i) acc[i] = zero;
    #pragma unroll
    for (int ks = 0; ks < 8; ++ks)
      #pragma unroll
      for (int tl = 0; tl < 4; ++tl)
        acc[tl] = __builtin_amdgcn_mfma_f32_16x16x32_bf16(a[ks], bfrag[tl][ks], acc[tl], 0, 0, 0);

    bf16* dst = UV + (size_t)(i0 + ii) * 4096;
    #pragma unroll
    for (int tl = 0; tl < 4; ++tl) {
      int n = w * 64 + tl * 16 + lr;
      #pragma unroll
      for (int r = 0; r < 4; ++r) {
        int m = quad * 4 + r;
        float v = acc[tl][r] + (m >= 6 ? bias[tl] : 0.f);
        dst[m * 256 + n] = __float2bfloat16(v);
      }
    }
  }
}

// ---- K3: out GEMM, split-K. Bs staged via async global_load_lds (swizzled by
//      per-lane global address permutation); As built from register-prefetched UV.
__global__ __launch_bounds__(256, 2) void out_gemm(
    const bf16* __restrict__ UV, const bf16* __restrict__ Wt,
    float* __restrict__ pbuf)
{
  __shared__ bf16 As[64 * 64];
  __shared__ bf16 Bs[256 * 64];   // wave w owns rows [64w, 64w+64)

  const int t = threadIdx.x;
  const int w = t >> 6, l = t & 63, lr = l & 15, quad = l >> 4;
  const int m0 = blockIdx.x * 64;
  const int ks0 = blockIdx.y * KSLICE;
  const int ar = t >> 2, ac = t & 3;

  // per-lane base pointers for async Bs staging: instruction q covers local
  // rows 8q..8q+7; lane l -> row 8q + (l>>3), global chunk j = (l&7)^(l>>3)
  // (this realizes the xor swizzle purely via the global address).
  const bf16* rowp[8];
  {
    int rl = l >> 3, j = (l & 7) ^ rl;
    #pragma unroll
    for (int q = 0; q < 8; ++q)
      rowp[q] = Wt + (size_t)(w * 64 + 8 * q + rl) * KO + ks0 + j * 8;
  }
  bf16* BsW = &Bs[w * 4096];

  floatx4 acc[16];
  floatx4 zero = {0.f, 0.f, 0.f, 0.f};
  #pragma unroll
  for (int i = 0; i < 16; ++i) acc[i] = zero;

  // prefetch uu/vv for it=0
  uint4 cu0, cu1, cv0, cv1;
  {
    const int combo = ks0 >> 8;
    const int urow = combo / 10, vrow = 6 + (combo - urow * 10);
    const int c0 = ks0 & 255;
    const bf16* ub = UV + ((size_t)(m0 + ar) * 16 + urow) * 256 + c0 + ac * 16;
    const bf16* vb = UV + ((size_t)(m0 + ar) * 16 + vrow) * 256 + c0 + ac * 16;
    cu0 = *(const uint4*)ub;  cu1 = *(const uint4*)(ub + 8);
    cv0 = *(const uint4*)vb;  cv1 = *(const uint4*)(vb + 8);
  }

  for (int it = 0; it < KSLICE / 64; ++it) {
    __syncthreads();   // A: prev iter's frag reads done; LDS reusable

    // issue async Bs staging for this iter (no VGPR round-trip)
    #pragma unroll
    for (int q = 0; q < 8; ++q)
      async_lds16(rowp[q] + it * 64, BsW + q * 512);

    // build As from prefetched uu/vv
    {
      uint4 h0, h1;
      h0.x = hpair(cu0.x, cv0.x); h0.y = hpair(cu0.y, cv0.y);
      h0.z = hpair(cu0.z, cv0.z); h0.w = hpair(cu0.w, cv0.w);
      h1.x = hpair(cu1.x, cv1.x); h1.y = hpair(cu1.y, cv1.y);
      h1.z = hpair(cu1.z, cv1.z); h1.w = hpair(cu1.w, cv1.w);
      int jA0 = (2 * ac) ^ (ar & 7);
      int jA1 = (2 * ac + 1) ^ (ar & 7);
      *(uint4*)&As[ar * 64 + jA0 * 8] = h0;
      *(uint4*)&As[ar * 64 + jA1 * 8] = h1;
    }

    __syncthreads();   // B: drains async Bs (vmcnt) + As ds_writes (lgkm)

    // prefetch uu/vv for next iter — issued now, consumed after next barrier A,
    // latency hidden behind the MFMA phase below
    if (it + 1 < KSLICE / 64) {
      const int gk2 = ks0 + (it + 1) * 64;
      const int combo = gk2 >> 8;
      const int urow = combo / 10, vrow = 6 + (combo - urow * 10);
      const int c0 = gk2 & 255;
      const bf16* ub = UV + ((size_t)(m0 + ar) * 16 + urow) * 256 + c0 + ac * 16;
      const bf16* vb = UV + ((size_t)(m0 + ar) * 16 + vrow) * 256 + c0 + ac * 16;
      cu0 = *(const uint4*)ub;  cu1 = *(const uint4*)(ub + 8);
      cv0 = *(const uint4*)vb;  cv1 = *(const uint4*)(vb + 8);
    }

    #pragma unroll
    for (int ks = 0; ks < 2; ++ks) {
      short8 af[4], bfr[4];
      #pragma unroll
      for (int i = 0; i < 4; ++i) {
        int row = i * 16 + lr;
        int jp = (4 * ks + quad) ^ (row & 7);
        af[i] = *(const short8*)&As[row * 64 + jp * 8];
      }
      #pragma unroll
      for (int j = 0; j < 4; ++j) {
        int row = w * 64 + j * 16 + lr;
        int jp = (4 * ks + quad) ^ (row & 7);
        bfr[j] = *(const short8*)&Bs[row * 64 + jp * 8];
      }
      #pragma unroll
      for (int i = 0; i < 4; ++i)
        #pragma unroll
        for (int j = 0; j < 4; ++j)
          acc[i * 4 + j] = __builtin_amdgcn_mfma_f32_16x16x32_bf16(af[i], bfr[j], acc[i * 4 + j], 0, 0, 0);
    }
  }

  // lane-linear coalesced partial store: [by][bx][w][q][l]
  float* dst = pbuf + (((size_t)blockIdx.y * 48 + blockIdx.x) * 4 + w) * 4096 + l;
  #pragma unroll
  for (int a = 0; a < 16; ++a)
    #pragma unroll
    for (int r = 0; r < 4; ++r)
      dst[(a * 4 + r) * 64] = acc[a][r];
}

// ---- K4: reduce split-K partials (permuted layout) + bias + lrelu
__global__ __launch_bounds__(256) void reduce_bias(
    const float* __restrict__ pbuf, const float* __restrict__ outb,
    float* __restrict__ out, int slice_stride)
{
  int idx = blockIdx.x * 256 + threadIdx.x;
  float s = 0.f;
  #pragma unroll
  for (int k = 0; k < KS; ++k) s += pbuf[idx + (size_t)k * slice_stride];
  int l = idx & 63, q = (idx >> 6) & 63, w = (idx >> 12) & 3, bx = idx >> 14;
  int a = q >> 2, r = q & 3, i = a >> 2, tl = a & 3;
  int lr = l & 15, quad = l >> 4;
  int m = bx * 64 + i * 16 + quad * 4 + r;
  int n = w * 64 + tl * 16 + lr;
  out[(size_t)m * 256 + n] = lrelu(s + outb[n]);
}

extern "C" void kernel_launch(void* const* d_in, const int* in_sizes, int n_in,
                              void* d_out, int out_size, void* d_ws, size_t ws_size,
                              hipStream_t stream)
{
  const int*   x        = (const int*)  d_in[0];
  const float* card_emb = (const float*)d_in[1];
  const float* hand_W   = (const float*)d_in[2];
  const float* hand_b   = (const float*)d_in[3];
  const float* board_W  = (const float*)d_in[4];
  const float* board_b  = (const float*)d_in[5];
  const float* hidden_W = (const float*)d_in[6];
  const float* hidden_b = (const float*)d_in[7];
  const float* out_W    = (const float*)d_in[8];
  const float* out_b    = (const float*)d_in[9];
  float* out = (float*)d_out;

  const int NI = in_sizes[0] / 18;   // 3072 items

  char* ws = (char*)d_ws;
  bf16* hWt  = (bf16*)ws;                                     // 128 KB
  bf16* oWt  = (bf16*)(ws + 131072);                          // 7.5 MB
  bf16* UV   = (bf16*)(ws + 131072 + 7864320);                // NI*4096*2 = 24 MB
  bf16* Abuf = (bf16*)(ws + 131072 + 7864320 + (size_t)NI * 8192);   // 24 MB
  float* pbuf = (float*)Abuf;   // reuses Abuf (dead after uv_gemm): KS*NI*256*4 = 37.7 MB

  transpose_k<<<dim3(4, 4),   256, 0, stream>>>(hidden_W, hWt, 256);
  transpose_k<<<dim3(240, 4), 256, 0, stream>>>(out_W,    oWt, KO);
  hb_pack<<<NI / 4, 256, 0, stream>>>(x, card_emb, hand_W, hand_b,
                                      board_W, board_b, Abuf);
  uv_gemm<<<NI / 6, 256, 0, stream>>>(Abuf, hWt, hidden_b, UV);
  out_gemm<<<dim3(NI / 64, KS), 256, 0, stream>>>(UV, oWt, pbuf);
  reduce_bias<<<NI, 256, 0, stream>>>(pbuf, out_b, out, NI * 256);
}